// Round 1
// baseline (750.856 us; speedup 1.0000x reference)
//
#include <hip/hip_runtime.h>
#include <math.h>

namespace {
constexpr int B_ = 16, C_ = 128, H_ = 96, W_ = 96;
constexpr int HW_ = H_ * W_;
constexpr int G_ = 4, S_ = 2;
constexpr int CO_ = 32;        // offset channels
constexpr int COUT_ = 64;
constexpr int HO_ = 192, WO_ = 192;
constexpr int CPG_ = C_ / G_;  // 32 channels per sampling group
constexpr int TH_ = 16, TW_ = 16;
constexpr int HALO_H = TH_ + 2, HALO_W = TW_ + 2;
constexpr int NPOS = HALO_H * HALO_W;  // 324
}

// ---------------- Kernel A: 1x1 conv (128 -> 32) + bias ----------------
__global__ __launch_bounds__(256) void k_off1(const float* __restrict__ x,
                                              const float* __restrict__ Wo1,
                                              const float* __restrict__ bo1,
                                              float* __restrict__ off1) {
  __shared__ float wT[C_ * CO_];  // transposed [c][o]
  __shared__ float bl[CO_];
  for (int i = threadIdx.x; i < C_ * CO_; i += 256) {
    int o = i >> 7;      // i / 128
    int c = i & 127;
    wT[c * CO_ + o] = Wo1[i];
  }
  if (threadIdx.x < CO_) bl[threadIdx.x] = bo1[threadIdx.x];
  __syncthreads();
  int p = blockIdx.x * 256 + threadIdx.x;  // exactly B*H*W threads
  int b = p / HW_, hw = p % HW_;
  float acc[CO_];
#pragma unroll
  for (int o = 0; o < CO_; ++o) acc[o] = bl[o];
  const float* xb = x + (size_t)b * C_ * HW_ + hw;
  for (int c = 0; c < C_; ++c) {
    float xv = xb[c * HW_];
    const float4* wp = (const float4*)&wT[c * CO_];
#pragma unroll
    for (int o4 = 0; o4 < CO_ / 4; ++o4) {
      float4 wv = wp[o4];
      acc[o4 * 4 + 0] = fmaf(xv, wv.x, acc[o4 * 4 + 0]);
      acc[o4 * 4 + 1] = fmaf(xv, wv.y, acc[o4 * 4 + 1]);
      acc[o4 * 4 + 2] = fmaf(xv, wv.z, acc[o4 * 4 + 2]);
      acc[o4 * 4 + 3] = fmaf(xv, wv.w, acc[o4 * 4 + 3]);
    }
  }
  float* ob = off1 + (size_t)b * CO_ * HW_ + hw;
#pragma unroll
  for (int o = 0; o < CO_; ++o) ob[o * HW_] = acc[o];
}

// ---- Kernel B: 3x3 dilated(2) conv (32->32, no bias) -> final sample coords ----
// coords layout: [B][G][HO][WO][2] (ix, iy) already clipped to [0, W-1]/[0, H-1]
__global__ __launch_bounds__(256) void k_coords(const float* __restrict__ off1,
                                                const float* __restrict__ Wo2,
                                                float* __restrict__ coords) {
  __shared__ float wT[CO_ * 9 * CO_];  // [(ci*9+k)][o], 9216 floats
  for (int i = threadIdx.x; i < CO_ * CO_ * 9; i += 256) {
    int o = i / 288;
    int r = i % 288;  // ci*9 + k
    wT[r * CO_ + o] = Wo2[i];
  }
  __syncthreads();
  int p = blockIdx.x * 256 + threadIdx.x;
  int b = p / HW_, hw = p % HW_;
  int h = hw / W_, w = hw % W_;
  float acc[CO_];
#pragma unroll
  for (int o = 0; o < CO_; ++o) acc[o] = 0.f;
  const float* ib = off1 + (size_t)b * CO_ * HW_;
#pragma unroll
  for (int ky = 0; ky < 3; ++ky) {
    int hh = h + 2 * (ky - 1);
    if (hh < 0 || hh >= H_) continue;
#pragma unroll
    for (int kx = 0; kx < 3; ++kx) {
      int ww = w + 2 * (kx - 1);
      if (ww < 0 || ww >= W_) continue;
      const float* ip = ib + hh * W_ + ww;
      int k = ky * 3 + kx;
      for (int ci = 0; ci < CO_; ++ci) {
        float v = ip[ci * HW_];
        const float4* wp = (const float4*)&wT[(ci * 9 + k) * CO_];
#pragma unroll
        for (int o4 = 0; o4 < CO_ / 4; ++o4) {
          float4 wv = wp[o4];
          acc[o4 * 4 + 0] = fmaf(v, wv.x, acc[o4 * 4 + 0]);
          acc[o4 * 4 + 1] = fmaf(v, wv.y, acc[o4 * 4 + 1]);
          acc[o4 * 4 + 2] = fmaf(v, wv.z, acc[o4 * 4 + 2]);
          acc[o4 * 4 + 3] = fmaf(v, wv.w, acc[o4 * 4 + 3]);
        }
      }
    }
  }
  // base coords + offset/G + init_pos, unnormalize (cancels exactly), clip border
  float cwv = (float)w + sinf((float)M_PI * (float)(w + 1) / (float)W_);
  float chv = (float)h + sinf((float)M_PI * (float)(h + 1) / (float)H_);
  float* cb = coords + (size_t)b * G_ * HO_ * WO_ * 2;
#pragma unroll
  for (int g = 0; g < G_; ++g) {
#pragma unroll
    for (int sh = 0; sh < S_; ++sh) {
#pragma unroll
      for (int sw = 0; sw < S_; ++sw) {
        int idx = g * 4 + sh * 2 + sw;
        float offx = acc[idx] * 0.25f + ((float)sw - 0.5f) * 0.5f;
        float offy = acc[16 + idx] * 0.25f + ((float)sh - 0.5f) * 0.5f;
        float ix = fminf(fmaxf(cwv + offx - 0.5f, 0.f), (float)(W_ - 1));
        float iy = fminf(fmaxf(chv + offy - 0.5f, 0.f), (float)(H_ - 1));
        int ho = 2 * h + sh, wo = 2 * w + sw;
        size_t oidx = (((size_t)g * HO_) + ho) * WO_ + wo;
        cb[oidx * 2 + 0] = ix;
        cb[oidx * 2 + 1] = iy;
      }
    }
  }
}

// -- Kernel C: fused grid_sample (per group, tiled to LDS) + dw3x3 + BN + ReLU + 1x1 conv --
__global__ __launch_bounds__(256) void k_fused(
    const float* __restrict__ x, const float* __restrict__ coords,
    const float* __restrict__ Wdw, const float* __restrict__ bn_gamma,
    const float* __restrict__ bn_beta, const float* __restrict__ bn_mean,
    const float* __restrict__ bn_var, const float* __restrict__ Wpw,
    const float* __restrict__ bpw, float* __restrict__ out) {
  __shared__ float up[CPG_][NPOS];    // 40.5 KB: one group's upsampled halo tile
  __shared__ float wpwT[C_ * COUT_];  // 32 KB, transposed [c][o]
  __shared__ float wdw[C_][9];
  __shared__ float bsc[C_], bbe[C_], bmu[C_], bp[COUT_];

  for (int i = threadIdx.x; i < C_ * COUT_; i += 256) {
    int o = i & 63;   // i % 64
    int c = i >> 6;   // i / 64  -- NOTE: Wpw is [o][c]; recompute properly below
    (void)o; (void)c;
    int oo = i / C_;      // output channel
    int cc = i % C_;      // input channel
    wpwT[cc * COUT_ + oo] = Wpw[i];
  }
  for (int i = threadIdx.x; i < C_ * 9; i += 256) wdw[i / 9][i % 9] = Wdw[i];
  for (int i = threadIdx.x; i < C_; i += 256) {
    bsc[i] = bn_gamma[i] * rsqrtf(bn_var[i] + 1e-5f);
    bbe[i] = bn_beta[i];
    bmu[i] = bn_mean[i];
  }
  if (threadIdx.x < COUT_) bp[threadIdx.x] = bpw[threadIdx.x];

  constexpr int TILES_W = WO_ / TW_;            // 12
  constexpr int TILES = TILES_W * (HO_ / TH_);  // 144
  int b = blockIdx.x / TILES;
  int t = blockIdx.x % TILES;
  int oh0 = (t / TILES_W) * TH_;
  int ow0 = (t % TILES_W) * TW_;
  int tid = threadIdx.x;
  int py = tid / TW_, px = tid % TW_;

  float acc[COUT_];
#pragma unroll
  for (int o = 0; o < COUT_; ++o) acc[o] = 0.f;

  for (int g = 0; g < G_; ++g) {
    __syncthreads();  // covers initial weight loads and protects `up` reuse
    const float* xg = x + ((size_t)b * C_ + g * CPG_) * HW_;
    const float* cbase = coords + (((size_t)b * G_ + g) * HO_ * WO_) * 2;
    for (int p = tid; p < NPOS; p += 256) {
      int hy = oh0 + p / HALO_W - 1;
      int hx = ow0 + p % HALO_W - 1;
      if (hy < 0 || hy >= HO_ || hx < 0 || hx >= WO_) {
        for (int cg = 0; cg < CPG_; ++cg) up[cg][p] = 0.f;  // dwconv zero pad
      } else {
        float ix = cbase[((size_t)hy * WO_ + hx) * 2 + 0];
        float iy = cbase[((size_t)hy * WO_ + hx) * 2 + 1];
        float x0f = floorf(ix), y0f = floorf(iy);
        float wx = ix - x0f, wy = iy - y0f;
        int x0 = (int)x0f, y0 = (int)y0f;          // already in [0, 95]
        int x1 = min(x0 + 1, W_ - 1);
        int y1 = min(y0 + 1, H_ - 1);
        float w00 = (1.f - wx) * (1.f - wy);
        float w01 = wx * (1.f - wy);
        float w10 = (1.f - wx) * wy;
        float w11 = wx * wy;
        const float* r0 = xg + y0 * W_;
        const float* r1 = xg + y1 * W_;
        for (int cg = 0; cg < CPG_; ++cg) {
          int off = cg * HW_;
          up[cg][p] = w00 * r0[off + x0] + w01 * r0[off + x1] +
                      w10 * r1[off + x0] + w11 * r1[off + x1];
        }
      }
    }
    __syncthreads();
#pragma unroll 4
    for (int cg = 0; cg < CPG_; ++cg) {
      int c = g * CPG_ + cg;
      const float* u = &up[cg][py * HALO_W + px];
      float dw = 0.f;
#pragma unroll
      for (int dy = 0; dy < 3; ++dy) {
#pragma unroll
        for (int dx = 0; dx < 3; ++dx)
          dw = fmaf(u[dy * HALO_W + dx], wdw[c][dy * 3 + dx], dw);
      }
      float yv = fmaf(dw - bmu[c], bsc[c], bbe[c]);
      yv = fmaxf(yv, 0.f);
      const float4* wp = (const float4*)&wpwT[c * COUT_];
#pragma unroll
      for (int o4 = 0; o4 < COUT_ / 4; ++o4) {
        float4 wv = wp[o4];
        acc[o4 * 4 + 0] = fmaf(yv, wv.x, acc[o4 * 4 + 0]);
        acc[o4 * 4 + 1] = fmaf(yv, wv.y, acc[o4 * 4 + 1]);
        acc[o4 * 4 + 2] = fmaf(yv, wv.z, acc[o4 * 4 + 2]);
        acc[o4 * 4 + 3] = fmaf(yv, wv.w, acc[o4 * 4 + 3]);
      }
    }
  }
  int oh = oh0 + py, ow = ow0 + px;
  float* ob = out + (size_t)b * COUT_ * HO_ * WO_ + (size_t)oh * WO_ + ow;
#pragma unroll
  for (int o = 0; o < COUT_; ++o) ob[(size_t)o * HO_ * WO_] = acc[o] + bp[o];
}

extern "C" void kernel_launch(void* const* d_in, const int* in_sizes, int n_in,
                              void* d_out, int out_size, void* d_ws, size_t ws_size,
                              hipStream_t stream) {
  const float* x        = (const float*)d_in[0];
  const float* Wo1      = (const float*)d_in[1];
  const float* bo1      = (const float*)d_in[2];
  const float* Wo2      = (const float*)d_in[3];
  const float* Wdw      = (const float*)d_in[4];
  const float* bn_gamma = (const float*)d_in[5];
  const float* bn_beta  = (const float*)d_in[6];
  const float* bn_mean  = (const float*)d_in[7];
  const float* bn_var   = (const float*)d_in[8];
  const float* Wpw      = (const float*)d_in[9];
  const float* bpw      = (const float*)d_in[10];
  float* out = (float*)d_out;

  float* off1   = (float*)d_ws;                         // [B,32,96,96]  18.9 MB
  float* coords = off1 + (size_t)B_ * CO_ * HW_;        // [B,G,192,192,2] 18.9 MB

  k_off1  <<<(B_ * HW_) / 256, 256, 0, stream>>>(x, Wo1, bo1, off1);
  k_coords<<<(B_ * HW_) / 256, 256, 0, stream>>>(off1, Wo2, coords);
  k_fused <<<B_ * 144, 256, 0, stream>>>(x, coords, Wdw, bn_gamma, bn_beta,
                                         bn_mean, bn_var, Wpw, bpw, out);
}

// Round 2
// 451.418 us; speedup vs baseline: 1.6633x; 1.6633x over previous
//
#include <hip/hip_runtime.h>
#include <math.h>

namespace {
constexpr int B_ = 16, C_ = 128, H_ = 96, W_ = 96;
constexpr int HW_ = H_ * W_;
constexpr int G_ = 4, S_ = 2;
constexpr int CO_ = 32;        // offset channels
constexpr int COUT_ = 64;
constexpr int HO_ = 192, WO_ = 192;
constexpr int CPG_ = C_ / G_;  // 32 channels per sampling group
constexpr int TH_ = 16, TW_ = 16;
constexpr int HALO_H = TH_ + 2, HALO_W = TW_ + 2;
constexpr int NPOS = HALO_H * HALO_W;  // 324
constexpr int UPS = CPG_ + 1;          // padded channel stride (33) -> <=2-way banks
}

// ---------------- Kernel P: transpose Wpw [o][c] -> [c][o] into ws ----------
__global__ __launch_bounds__(256) void k_prep(const float* __restrict__ Wpw,
                                              float* __restrict__ wpwT) {
  int i = blockIdx.x * 256 + threadIdx.x;
  if (i < C_ * COUT_) {
    int o = i / C_, c = i % C_;
    wpwT[c * COUT_ + o] = Wpw[i];
  }
}

// ---------------- Kernel A: 1x1 conv (128 -> 32) + bias ----------------
__global__ __launch_bounds__(256) void k_off1(const float* __restrict__ x,
                                              const float* __restrict__ Wo1,
                                              const float* __restrict__ bo1,
                                              float* __restrict__ off1) {
  __shared__ float wT[C_ * CO_];  // transposed [c][o]
  __shared__ float bl[CO_];
  for (int i = threadIdx.x; i < C_ * CO_; i += 256) {
    int o = i >> 7;
    int c = i & 127;
    wT[c * CO_ + o] = Wo1[i];
  }
  if (threadIdx.x < CO_) bl[threadIdx.x] = bo1[threadIdx.x];
  __syncthreads();
  int p = blockIdx.x * 256 + threadIdx.x;  // exactly B*H*W threads
  int b = p / HW_, hw = p % HW_;
  float acc[CO_];
#pragma unroll
  for (int o = 0; o < CO_; ++o) acc[o] = bl[o];
  const float* xb = x + (size_t)b * C_ * HW_ + hw;
  for (int c = 0; c < C_; ++c) {
    float xv = xb[c * HW_];
    const float4* wp = (const float4*)&wT[c * CO_];
#pragma unroll
    for (int o4 = 0; o4 < CO_ / 4; ++o4) {
      float4 wv = wp[o4];
      acc[o4 * 4 + 0] = fmaf(xv, wv.x, acc[o4 * 4 + 0]);
      acc[o4 * 4 + 1] = fmaf(xv, wv.y, acc[o4 * 4 + 1]);
      acc[o4 * 4 + 2] = fmaf(xv, wv.z, acc[o4 * 4 + 2]);
      acc[o4 * 4 + 3] = fmaf(xv, wv.w, acc[o4 * 4 + 3]);
    }
  }
  float* ob = off1 + (size_t)b * CO_ * HW_ + hw;
#pragma unroll
  for (int o = 0; o < CO_; ++o) ob[o * HW_] = acc[o];
}

// ---- Kernel B: 3x3 dilated(2) conv (32->32, no bias) -> final sample coords ----
// coords layout: [B][G][HO][WO][2] (ix, iy) already clipped to [0, W-1]/[0, H-1]
__global__ __launch_bounds__(256) void k_coords(const float* __restrict__ off1,
                                                const float* __restrict__ Wo2,
                                                float* __restrict__ coords) {
  __shared__ float wT[CO_ * 9 * CO_];  // [(ci*9+k)][o], 9216 floats
  for (int i = threadIdx.x; i < CO_ * CO_ * 9; i += 256) {
    int o = i / 288;
    int r = i % 288;  // ci*9 + k
    wT[r * CO_ + o] = Wo2[i];
  }
  __syncthreads();
  int p = blockIdx.x * 256 + threadIdx.x;
  int b = p / HW_, hw = p % HW_;
  int h = hw / W_, w = hw % W_;
  float acc[CO_];
#pragma unroll
  for (int o = 0; o < CO_; ++o) acc[o] = 0.f;
  const float* ib = off1 + (size_t)b * CO_ * HW_;
#pragma unroll
  for (int ky = 0; ky < 3; ++ky) {
    int hh = h + 2 * (ky - 1);
    if (hh < 0 || hh >= H_) continue;
#pragma unroll
    for (int kx = 0; kx < 3; ++kx) {
      int ww = w + 2 * (kx - 1);
      if (ww < 0 || ww >= W_) continue;
      const float* ip = ib + hh * W_ + ww;
      int k = ky * 3 + kx;
      for (int ci = 0; ci < CO_; ++ci) {
        float v = ip[ci * HW_];
        const float4* wp = (const float4*)&wT[(ci * 9 + k) * CO_];
#pragma unroll
        for (int o4 = 0; o4 < CO_ / 4; ++o4) {
          float4 wv = wp[o4];
          acc[o4 * 4 + 0] = fmaf(v, wv.x, acc[o4 * 4 + 0]);
          acc[o4 * 4 + 1] = fmaf(v, wv.y, acc[o4 * 4 + 1]);
          acc[o4 * 4 + 2] = fmaf(v, wv.z, acc[o4 * 4 + 2]);
          acc[o4 * 4 + 3] = fmaf(v, wv.w, acc[o4 * 4 + 3]);
        }
      }
    }
  }
  float cwv = (float)w + sinf((float)M_PI * (float)(w + 1) / (float)W_);
  float chv = (float)h + sinf((float)M_PI * (float)(h + 1) / (float)H_);
  float* cb = coords + (size_t)b * G_ * HO_ * WO_ * 2;
#pragma unroll
  for (int g = 0; g < G_; ++g) {
#pragma unroll
    for (int sh = 0; sh < S_; ++sh) {
#pragma unroll
      for (int sw = 0; sw < S_; ++sw) {
        int idx = g * 4 + sh * 2 + sw;
        float offx = acc[idx] * 0.25f + ((float)sw - 0.5f) * 0.5f;
        float offy = acc[16 + idx] * 0.25f + ((float)sh - 0.5f) * 0.5f;
        float ix = fminf(fmaxf(cwv + offx - 0.5f, 0.f), (float)(W_ - 1));
        float iy = fminf(fmaxf(chv + offy - 0.5f, 0.f), (float)(H_ - 1));
        int ho = 2 * h + sh, wo = 2 * w + sw;
        size_t oidx = (((size_t)g * HO_) + ho) * WO_ + wo;
        cb[oidx * 2 + 0] = ix;
        cb[oidx * 2 + 1] = iy;
      }
    }
  }
}

// -- Kernel C: fused grid_sample (tiled to LDS) + dw3x3 + BN + ReLU + 1x1 conv --
// up is [pos][channel] (stride 33): write lanes differ in pos -> <=2-way;
// stencil read lanes differ in pos -> <=2-way. wpwT read from global (wave-
// uniform address, L1 broadcast) so LDS stays under 50 KB -> 3 blocks/CU.
__global__ __launch_bounds__(256) void k_fused(
    const float* __restrict__ x, const float* __restrict__ coords,
    const float* __restrict__ wpwT, const float* __restrict__ Wdw,
    const float* __restrict__ bn_gamma, const float* __restrict__ bn_beta,
    const float* __restrict__ bn_mean, const float* __restrict__ bn_var,
    const float* __restrict__ bpw, float* __restrict__ out) {
  __shared__ float up[NPOS][UPS];     // 42.8 KB
  __shared__ float wdw[C_][9];        // 4.5 KB
  __shared__ float bsc[C_], bbe[C_], bmu[C_], bp[COUT_];

  for (int i = threadIdx.x; i < C_ * 9; i += 256) wdw[i / 9][i % 9] = Wdw[i];
  for (int i = threadIdx.x; i < C_; i += 256) {
    bsc[i] = bn_gamma[i] * rsqrtf(bn_var[i] + 1e-5f);
    bbe[i] = bn_beta[i];
    bmu[i] = bn_mean[i];
  }
  if (threadIdx.x < COUT_) bp[threadIdx.x] = bpw[threadIdx.x];

  constexpr int TILES_W = WO_ / TW_;            // 12
  constexpr int TILES = TILES_W * (HO_ / TH_);  // 144
  int b = blockIdx.x / TILES;
  int t = blockIdx.x % TILES;
  int oh0 = (t / TILES_W) * TH_;
  int ow0 = (t % TILES_W) * TW_;
  int tid = threadIdx.x;
  int py = tid / TW_, px = tid % TW_;

  float acc[COUT_];
#pragma unroll
  for (int o = 0; o < COUT_; ++o) acc[o] = 0.f;

  for (int g = 0; g < G_; ++g) {
    __syncthreads();  // covers initial weight loads and protects `up` reuse
    const float* xg = x + ((size_t)b * C_ + g * CPG_) * HW_;
    const float* cbase = coords + (((size_t)b * G_ + g) * HO_ * WO_) * 2;
    // sampling: work item = (position, channel-octet); 1296 items, 32 loads in
    // flight per item -> much shallower latency chain than 1 thread/position.
    for (int wi = tid; wi < NPOS * 4; wi += 256) {
      int p = wi >> 2, cq = wi & 3;
      int hy = oh0 + p / HALO_W - 1;
      int hx = ow0 + p % HALO_W - 1;
      float* dst = &up[p][cq * 8];
      if (hy < 0 || hy >= HO_ || hx < 0 || hx >= WO_) {
#pragma unroll
        for (int j = 0; j < 8; ++j) dst[j] = 0.f;  // dwconv zero pad
      } else {
        float2 c2 = *(const float2*)&cbase[((size_t)hy * WO_ + hx) * 2];
        float ix = c2.x, iy = c2.y;
        float x0f = floorf(ix), y0f = floorf(iy);
        float wx = ix - x0f, wy = iy - y0f;
        int x0 = (int)x0f, y0 = (int)y0f;  // already in [0, 95]
        int x1 = min(x0 + 1, W_ - 1);
        int y1 = min(y0 + 1, H_ - 1);
        float w00 = (1.f - wx) * (1.f - wy);
        float w01 = wx * (1.f - wy);
        float w10 = (1.f - wx) * wy;
        float w11 = wx * wy;
        const float* r0 = xg + (size_t)cq * 8 * HW_ + y0 * W_;
        const float* r1 = xg + (size_t)cq * 8 * HW_ + y1 * W_;
#pragma unroll
        for (int j = 0; j < 8; ++j) {
          int off = j * HW_;
          dst[j] = w00 * r0[off + x0] + w01 * r0[off + x1] +
                   w10 * r1[off + x0] + w11 * r1[off + x1];
        }
      }
    }
    __syncthreads();
#pragma unroll 4
    for (int cg = 0; cg < CPG_; ++cg) {
      int c = g * CPG_ + cg;
      const float* u = &up[py * HALO_W + px][cg];
      float dw = 0.f;
#pragma unroll
      for (int dy = 0; dy < 3; ++dy) {
#pragma unroll
        for (int dx = 0; dx < 3; ++dx)
          dw = fmaf(u[(dy * HALO_W + dx) * UPS], wdw[c][dy * 3 + dx], dw);
      }
      float yv = fmaf(dw - bmu[c], bsc[c], bbe[c]);
      yv = fmaxf(yv, 0.f);
      const float4* wp = (const float4*)&wpwT[c * COUT_];  // uniform, L1
#pragma unroll
      for (int o4 = 0; o4 < COUT_ / 4; ++o4) {
        float4 wv = wp[o4];
        acc[o4 * 4 + 0] = fmaf(yv, wv.x, acc[o4 * 4 + 0]);
        acc[o4 * 4 + 1] = fmaf(yv, wv.y, acc[o4 * 4 + 1]);
        acc[o4 * 4 + 2] = fmaf(yv, wv.z, acc[o4 * 4 + 2]);
        acc[o4 * 4 + 3] = fmaf(yv, wv.w, acc[o4 * 4 + 3]);
      }
    }
  }
  int oh = oh0 + py, ow = ow0 + px;
  float* ob = out + (size_t)b * COUT_ * HO_ * WO_ + (size_t)oh * WO_ + ow;
#pragma unroll
  for (int o = 0; o < COUT_; ++o) ob[(size_t)o * HO_ * WO_] = acc[o] + bp[o];
}

extern "C" void kernel_launch(void* const* d_in, const int* in_sizes, int n_in,
                              void* d_out, int out_size, void* d_ws, size_t ws_size,
                              hipStream_t stream) {
  const float* x        = (const float*)d_in[0];
  const float* Wo1      = (const float*)d_in[1];
  const float* bo1      = (const float*)d_in[2];
  const float* Wo2      = (const float*)d_in[3];
  const float* Wdw      = (const float*)d_in[4];
  const float* bn_gamma = (const float*)d_in[5];
  const float* bn_beta  = (const float*)d_in[6];
  const float* bn_mean  = (const float*)d_in[7];
  const float* bn_var   = (const float*)d_in[8];
  const float* Wpw      = (const float*)d_in[9];
  const float* bpw      = (const float*)d_in[10];
  float* out = (float*)d_out;

  float* off1   = (float*)d_ws;                          // [B,32,96,96]   18.9 MB
  float* coords = off1 + (size_t)B_ * CO_ * HW_;         // [B,G,192,192,2] 18.9 MB
  float* wpwT   = coords + (size_t)B_ * G_ * HO_ * WO_ * 2;  // [128][64] 32 KB

  k_prep  <<<(C_ * COUT_ + 255) / 256, 256, 0, stream>>>(Wpw, wpwT);
  k_off1  <<<(B_ * HW_) / 256, 256, 0, stream>>>(x, Wo1, bo1, off1);
  k_coords<<<(B_ * HW_) / 256, 256, 0, stream>>>(off1, Wo2, coords);
  k_fused <<<B_ * 144, 256, 0, stream>>>(x, coords, wpwT, Wdw, bn_gamma,
                                         bn_beta, bn_mean, bn_var, bpw, out);
}

// Round 4
// 422.671 us; speedup vs baseline: 1.7765x; 1.0680x over previous
//
#include <hip/hip_runtime.h>
#include <math.h>

typedef _Float16 f16x8 __attribute__((ext_vector_type(8)));
typedef _Float16 f16x2 __attribute__((ext_vector_type(2)));
typedef float f32x4 __attribute__((ext_vector_type(4)));

namespace {
constexpr int B_ = 16, C_ = 128, H_ = 96, W_ = 96;
constexpr int HW_ = H_ * W_;
constexpr int G_ = 4, S_ = 2;
constexpr int CO_ = 32;        // offset channels
constexpr int COUT_ = 64;
constexpr int HO_ = 192, WO_ = 192;
constexpr int CPG_ = C_ / G_;  // 32 channels per sampling group
constexpr int TH_ = 16, TW_ = 16;
constexpr int HALO_H = TH_ + 2, HALO_W = TW_ + 2;
constexpr int NPOS = HALO_H * HALO_W;   // 324
constexpr int UPS_F = 34;    // up row stride (f16): word-stride 17 -> conflict-free
constexpr int YROW = 40;     // y_lds row stride (f16): 80 B, 16B-multiple for b128
constexpr int UP_BYTES = NPOS * UPS_F * 2;         // 22032
constexpr int Y_BYTES = 256 * YROW * 2;            // 20480
constexpr int POOL_BYTES = UP_BYTES + Y_BYTES;     // 42512 (>= 32*257*4 c_lds overlay)
}

// ------------- Kernel P: cast Wpw [o][c] fp32 -> fp16 (same layout) ----------
__global__ __launch_bounds__(256) void k_prep(const float* __restrict__ Wpw,
                                              _Float16* __restrict__ wpwH) {
  int i = blockIdx.x * 256 + threadIdx.x;
  if (i < C_ * COUT_) wpwH[i] = (_Float16)Wpw[i];
}

// ---------------- Kernel A: 1x1 conv (128 -> 32) + bias ----------------
__global__ __launch_bounds__(256) void k_off1(const float* __restrict__ x,
                                              const float* __restrict__ Wo1,
                                              const float* __restrict__ bo1,
                                              float* __restrict__ off1) {
  __shared__ float wT[C_ * CO_];  // transposed [c][o]
  __shared__ float bl[CO_];
  for (int i = threadIdx.x; i < C_ * CO_; i += 256) {
    int o = i >> 7;
    int c = i & 127;
    wT[c * CO_ + o] = Wo1[i];
  }
  if (threadIdx.x < CO_) bl[threadIdx.x] = bo1[threadIdx.x];
  __syncthreads();
  int p = blockIdx.x * 256 + threadIdx.x;  // exactly B*H*W threads
  int b = p / HW_, hw = p % HW_;
  float acc[CO_];
#pragma unroll
  for (int o = 0; o < CO_; ++o) acc[o] = bl[o];
  const float* xb = x + (size_t)b * C_ * HW_ + hw;
  for (int c = 0; c < C_; ++c) {
    float xv = xb[c * HW_];
    const float4* wp = (const float4*)&wT[c * CO_];
#pragma unroll
    for (int o4 = 0; o4 < CO_ / 4; ++o4) {
      float4 wv = wp[o4];
      acc[o4 * 4 + 0] = fmaf(xv, wv.x, acc[o4 * 4 + 0]);
      acc[o4 * 4 + 1] = fmaf(xv, wv.y, acc[o4 * 4 + 1]);
      acc[o4 * 4 + 2] = fmaf(xv, wv.z, acc[o4 * 4 + 2]);
      acc[o4 * 4 + 3] = fmaf(xv, wv.w, acc[o4 * 4 + 3]);
    }
  }
  float* ob = off1 + (size_t)b * CO_ * HW_ + hw;
#pragma unroll
  for (int o = 0; o < CO_; ++o) ob[o * HW_] = acc[o];
}

// ---- Kernel B: 3x3 dilated(2) conv (32->32, no bias) -> final sample coords ----
__global__ __launch_bounds__(256) void k_coords(const float* __restrict__ off1,
                                                const float* __restrict__ Wo2,
                                                float* __restrict__ coords) {
  __shared__ float wT[CO_ * 9 * CO_];  // [(ci*9+k)][o]
  for (int i = threadIdx.x; i < CO_ * CO_ * 9; i += 256) {
    int o = i / 288;
    int r = i % 288;  // ci*9 + k
    wT[r * CO_ + o] = Wo2[i];
  }
  __syncthreads();
  int p = blockIdx.x * 256 + threadIdx.x;
  int b = p / HW_, hw = p % HW_;
  int h = hw / W_, w = hw % W_;
  float acc[CO_];
#pragma unroll
  for (int o = 0; o < CO_; ++o) acc[o] = 0.f;
  const float* ib = off1 + (size_t)b * CO_ * HW_;
#pragma unroll
  for (int ky = 0; ky < 3; ++ky) {
    int hh = h + 2 * (ky - 1);
    if (hh < 0 || hh >= H_) continue;
#pragma unroll
    for (int kx = 0; kx < 3; ++kx) {
      int ww = w + 2 * (kx - 1);
      if (ww < 0 || ww >= W_) continue;
      const float* ip = ib + hh * W_ + ww;
      int k = ky * 3 + kx;
      for (int ci = 0; ci < CO_; ++ci) {
        float v = ip[ci * HW_];
        const float4* wp = (const float4*)&wT[(ci * 9 + k) * CO_];
#pragma unroll
        for (int o4 = 0; o4 < CO_ / 4; ++o4) {
          float4 wv = wp[o4];
          acc[o4 * 4 + 0] = fmaf(v, wv.x, acc[o4 * 4 + 0]);
          acc[o4 * 4 + 1] = fmaf(v, wv.y, acc[o4 * 4 + 1]);
          acc[o4 * 4 + 2] = fmaf(v, wv.z, acc[o4 * 4 + 2]);
          acc[o4 * 4 + 3] = fmaf(v, wv.w, acc[o4 * 4 + 3]);
        }
      }
    }
  }
  float cwv = (float)w + sinf((float)M_PI * (float)(w + 1) / (float)W_);
  float chv = (float)h + sinf((float)M_PI * (float)(h + 1) / (float)H_);
  float* cb = coords + (size_t)b * G_ * HO_ * WO_ * 2;
#pragma unroll
  for (int g = 0; g < G_; ++g) {
#pragma unroll
    for (int sh = 0; sh < S_; ++sh) {
#pragma unroll
      for (int sw = 0; sw < S_; ++sw) {
        int idx = g * 4 + sh * 2 + sw;
        float offx = acc[idx] * 0.25f + ((float)sw - 0.5f) * 0.5f;
        float offy = acc[16 + idx] * 0.25f + ((float)sh - 0.5f) * 0.5f;
        float ix = fminf(fmaxf(cwv + offx - 0.5f, 0.f), (float)(W_ - 1));
        float iy = fminf(fmaxf(chv + offy - 0.5f, 0.f), (float)(H_ - 1));
        int ho = 2 * h + sh, wo = 2 * w + sw;
        size_t oidx = (((size_t)g * HO_) + ho) * WO_ + wo;
        cb[oidx * 2 + 0] = ix;
        cb[oidx * 2 + 1] = iy;
      }
    }
  }
}

// -- Kernel C: grid_sample (fp16 LDS tile) + dw3x3 + BN + ReLU + MFMA 1x1 conv --
__global__ __launch_bounds__(256, 3) void k_fused(
    const float* __restrict__ x, const float* __restrict__ coords,
    const _Float16* __restrict__ wpwH, const float* __restrict__ Wdw,
    const float* __restrict__ bn_gamma, const float* __restrict__ bn_beta,
    const float* __restrict__ bn_mean, const float* __restrict__ bn_var,
    const float* __restrict__ bpw, float* __restrict__ out) {
  __shared__ __align__(16) unsigned char pool[POOL_BYTES];  // up + y_lds; c_lds overlay
  __shared__ float wdwT[9][C_];  // [tap][channel] so (c,c+1) pairs are adjacent
  __shared__ float bsc[C_], bbe[C_], bmu[C_], bp[COUT_];

  _Float16 (*up)[UPS_F] = (_Float16(*)[UPS_F])pool;
  _Float16 (*ylds)[YROW] = (_Float16(*)[YROW])(pool + UP_BYTES);

  for (int i = threadIdx.x; i < C_ * 9; i += 256) wdwT[i % 9][i / 9] = Wdw[i];
  for (int i = threadIdx.x; i < C_; i += 256) {
    bsc[i] = bn_gamma[i] * rsqrtf(bn_var[i] + 1e-5f);
    bbe[i] = bn_beta[i];
    bmu[i] = bn_mean[i];
  }
  if (threadIdx.x < COUT_) bp[threadIdx.x] = bpw[threadIdx.x];

  constexpr int TILES_W = WO_ / TW_;            // 12
  constexpr int TILES = TILES_W * (HO_ / TH_);  // 144
  int b = blockIdx.x / TILES;
  int t = blockIdx.x % TILES;
  int oh0 = (t / TILES_W) * TH_;
  int ow0 = (t % TILES_W) * TW_;
  int tid = threadIdx.x;
  int py = tid / TW_, px = tid % TW_;
  int lane = tid & 63, wv_ = tid >> 6;
  int lr = lane & 15, lk = lane >> 4;

  f32x4 acc[4][4];
#pragma unroll
  for (int mt = 0; mt < 4; ++mt)
#pragma unroll
    for (int nt = 0; nt < 4; ++nt) acc[mt][nt] = (f32x4){0.f, 0.f, 0.f, 0.f};

  for (int g = 0; g < G_; ++g) {
    __syncthreads();  // covers init loads; protects up/ylds reuse across g
    const float* xg = x + ((size_t)b * C_ + g * CPG_) * HW_;
    const float* cbase = coords + (((size_t)b * G_ + g) * HO_ * WO_) * 2;
    // ---- sampling: work item = (halo position, channel-octet) ----
    for (int wi = tid; wi < NPOS * 4; wi += 256) {
      int p = wi >> 2, cq = wi & 3;
      int hy = oh0 + p / HALO_W - 1;
      int hx = ow0 + p % HALO_W - 1;
      _Float16* dst = &up[p][cq * 8];
      if (hy < 0 || hy >= HO_ || hx < 0 || hx >= WO_) {
#pragma unroll
        for (int j2 = 0; j2 < 4; ++j2)
          *(f16x2*)&dst[2 * j2] = (f16x2){(_Float16)0.f, (_Float16)0.f};
      } else {
        float2 c2 = *(const float2*)&cbase[((size_t)hy * WO_ + hx) * 2];
        float ix = c2.x, iy = c2.y;
        float x0f = floorf(ix), y0f = floorf(iy);
        float wx = ix - x0f, wy = iy - y0f;
        int x0 = (int)x0f, y0 = (int)y0f;  // already in [0, 95]
        int x1 = min(x0 + 1, W_ - 1);
        int y1 = min(y0 + 1, H_ - 1);
        float w00 = (1.f - wx) * (1.f - wy);
        float w01 = wx * (1.f - wy);
        float w10 = (1.f - wx) * wy;
        float w11 = wx * wy;
        const float* r0 = xg + (size_t)(cq * 8) * HW_ + y0 * W_;
        const float* r1 = xg + (size_t)(cq * 8) * HW_ + y1 * W_;
#pragma unroll
        for (int j2 = 0; j2 < 4; ++j2) {
          int offA = (2 * j2) * HW_, offB = offA + HW_;
          float v0 = w00 * r0[offA + x0] + w01 * r0[offA + x1] +
                     w10 * r1[offA + x0] + w11 * r1[offA + x1];
          float v1 = w00 * r0[offB + x0] + w01 * r0[offB + x1] +
                     w10 * r1[offB + x0] + w11 * r1[offB + x1];
          *(f16x2*)&dst[2 * j2] = (f16x2){(_Float16)v0, (_Float16)v1};
        }
      }
    }
    __syncthreads();
    // ---- dw3x3 + BN + ReLU -> y_lds (fp16 A-tile [256 pix][32 ch]) ----
#pragma unroll 4
    for (int cp = 0; cp < CPG_ / 2; ++cp) {
      int cl = cp * 2;          // channel-pair within group
      int c = g * CPG_ + cl;    // global channel
      float dw0 = 0.f, dw1 = 0.f;
#pragma unroll
      for (int dy = 0; dy < 3; ++dy) {
#pragma unroll
        for (int dx = 0; dx < 3; ++dx) {
          f16x2 pk = *(const f16x2*)&up[(py + dy) * HALO_W + px + dx][cl];
          float2 wdv = *(const float2*)&wdwT[dy * 3 + dx][c];
          dw0 = fmaf((float)pk.x, wdv.x, dw0);
          dw1 = fmaf((float)pk.y, wdv.y, dw1);
        }
      }
      float2 sc = *(const float2*)&bsc[c];
      float2 be = *(const float2*)&bbe[c];
      float2 mu = *(const float2*)&bmu[c];
      float y0 = fmaxf(fmaf(dw0 - mu.x, sc.x, be.x), 0.f);
      float y1 = fmaxf(fmaf(dw1 - mu.y, sc.y, be.y), 0.f);
      *(f16x2*)&ylds[tid][cl] = (f16x2){(_Float16)y0, (_Float16)y1};
    }
    __syncthreads();
    // ---- MFMA: [256 pix x 32 ch] @ [32 ch x 64 out], fp32 accum ----
    f16x8 afr[4];
#pragma unroll
    for (int mt = 0; mt < 4; ++mt)
      afr[mt] = *(const f16x8*)&ylds[(wv_ * 4 + mt) * 16 + lr][lk * 8];
#pragma unroll
    for (int nt = 0; nt < 4; ++nt) {
      f16x8 bfr = *(const f16x8*)&wpwH[(nt * 16 + lr) * C_ + g * CPG_ + lk * 8];
#pragma unroll
      for (int mt = 0; mt < 4; ++mt)
        acc[mt][nt] = __builtin_amdgcn_mfma_f32_16x16x32_f16(afr[mt], bfr,
                                                             acc[mt][nt], 0, 0, 0);
    }
  }

  // ---- epilogue: transpose C through LDS (overlay) for coalesced writes ----
  float (*clds)[257] = (float(*)[257])pool;  // [32][256+1]
  int oh = oh0 + py, ow = ow0 + px;
#pragma unroll
  for (int h = 0; h < 2; ++h) {
    __syncthreads();  // first iter: all waves done reading ylds/up
#pragma unroll
    for (int nh = 0; nh < 2; ++nh) {
      int nt = 2 * h + nh;
#pragma unroll
      for (int mt = 0; mt < 4; ++mt) {
#pragma unroll
        for (int r = 0; r < 4; ++r)
          clds[nh * 16 + lr][(wv_ * 4 + mt) * 16 + lk * 4 + r] = acc[mt][nt][r];
      }
    }
    __syncthreads();
#pragma unroll 4
    for (int i = 0; i < 32; ++i) {
      int o = 32 * h + i;
      out[(((size_t)b * COUT_ + o) * HO_ + oh) * WO_ + ow] = clds[i][tid] + bp[o];
    }
  }
}

extern "C" void kernel_launch(void* const* d_in, const int* in_sizes, int n_in,
                              void* d_out, int out_size, void* d_ws, size_t ws_size,
                              hipStream_t stream) {
  const float* x        = (const float*)d_in[0];
  const float* Wo1      = (const float*)d_in[1];
  const float* bo1      = (const float*)d_in[2];
  const float* Wo2      = (const float*)d_in[3];
  const float* Wdw      = (const float*)d_in[4];
  const float* bn_gamma = (const float*)d_in[5];
  const float* bn_beta  = (const float*)d_in[6];
  const float* bn_mean  = (const float*)d_in[7];
  const float* bn_var   = (const float*)d_in[8];
  const float* Wpw      = (const float*)d_in[9];
  const float* bpw      = (const float*)d_in[10];
  float* out = (float*)d_out;

  float* off1   = (float*)d_ws;                          // [B,32,96,96]    18.9 MB
  float* coords = off1 + (size_t)B_ * CO_ * HW_;         // [B,G,192,192,2] 18.9 MB
  _Float16* wpwH = (_Float16*)(coords + (size_t)B_ * G_ * HO_ * WO_ * 2);

  k_prep  <<<(C_ * COUT_ + 255) / 256, 256, 0, stream>>>(Wpw, wpwH);
  k_off1  <<<(B_ * HW_) / 256, 256, 0, stream>>>(x, Wo1, bo1, off1);
  k_coords<<<(B_ * HW_) / 256, 256, 0, stream>>>(off1, Wo2, coords);
  k_fused <<<B_ * 144, 256, 0, stream>>>(x, coords, wpwH, Wdw, bn_gamma,
                                         bn_beta, bn_mean, bn_var, bpw, out);
}

// Round 5
// 398.438 us; speedup vs baseline: 1.8845x; 1.0608x over previous
//
#include <hip/hip_runtime.h>
#include <math.h>

typedef _Float16 f16x8 __attribute__((ext_vector_type(8)));
typedef _Float16 f16x2 __attribute__((ext_vector_type(2)));
typedef float f32x4 __attribute__((ext_vector_type(4)));

namespace {
constexpr int B_ = 16, C_ = 128, H_ = 96, W_ = 96;
constexpr int HW_ = H_ * W_;
constexpr int G_ = 4, S_ = 2;
constexpr int CO_ = 32;        // offset channels
constexpr int COUT_ = 64;
constexpr int HO_ = 192, WO_ = 192;
constexpr int CPG_ = C_ / G_;  // 32 channels per sampling group
constexpr int TH_ = 16, TW_ = 16;
constexpr int HALO_H = TH_ + 2, HALO_W = TW_ + 2;
constexpr int NPOS = HALO_H * HALO_W;   // 324
constexpr int UPS_F = 34;    // up row stride (f16): word-stride 17 -> conflict-free
constexpr int YROW16 = 24;   // ylds16 row stride (f16): 48 B, 16B-multiple
constexpr int UP_BYTES = NPOS * UPS_F * 2;         // 22032
constexpr int Y_BYTES = 256 * YROW16 * 2;          // 12288
constexpr int POOL_BYTES = UP_BYTES + Y_BYTES;     // 34320 (>= 16*257*4 clds overlay)

// ws float offsets
constexpr size_t WS_OFF1   = 0;                                   // [B,32,96,96]
constexpr size_t WS_COORDS = (size_t)B_ * CO_ * HW_;              // [B,G,HO,WO,2]
constexpr size_t WS_WPWH   = WS_COORDS + (size_t)B_ * G_ * HO_ * WO_ * 2;  // f16[64*128]
constexpr size_t WS_WO1T   = WS_WPWH + (C_ * COUT_) / 2;          // f32[128*32]
constexpr size_t WS_WO2T   = WS_WO1T + C_ * CO_;                  // f32[288*32]
}

// --- Kernel P: Wpw->fp16; Wo1 [o][c]->[c][o]; Wo2 [o][ci*9+k]->[ci*9+k][o] ---
__global__ __launch_bounds__(256) void k_prep(const float* __restrict__ Wpw,
                                              const float* __restrict__ Wo1,
                                              const float* __restrict__ Wo2,
                                              _Float16* __restrict__ wpwH,
                                              float* __restrict__ wo1T,
                                              float* __restrict__ wo2T) {
  int i = blockIdx.x * 256 + threadIdx.x;  // grid covers exactly 21504
  if (i < C_ * COUT_) {
    wpwH[i] = (_Float16)Wpw[i];
  } else if (i < C_ * COUT_ + C_ * CO_) {
    int j = i - C_ * COUT_;
    int o = j >> 7, c = j & 127;   // Wo1 is [32][128]
    wo1T[c * CO_ + o] = Wo1[j];
  } else {
    int j = i - C_ * COUT_ - C_ * CO_;  // Wo2 is [32][288]
    int o = j / 288, r = j % 288;
    wo2T[r * CO_ + o] = Wo2[j];
  }
}

// ------- Kernel A: 1x1 conv (128 -> 32) + bias, 2 px/thread (float2) --------
__global__ __launch_bounds__(256) void k_off1(const float* __restrict__ x,
                                              const float* __restrict__ wo1T,
                                              const float* __restrict__ bo1,
                                              float* __restrict__ off1) {
  constexpr int HW2 = HW_ / 2;
  int p2 = blockIdx.x * 256 + threadIdx.x;  // B*HW/2 = 73728 threads
  int b = p2 / HW2, r = p2 % HW2;
  const float2* xb = (const float2*)(x + (size_t)b * C_ * HW_) + r;
  float2 acc[CO_];
#pragma unroll
  for (int o = 0; o < CO_; ++o) { float bv = bo1[o]; acc[o].x = bv; acc[o].y = bv; }
  for (int c = 0; c < C_; ++c) {
    float2 xv = xb[c * HW2];
    const float* wr = wo1T + c * CO_;  // uniform address -> scalar loads
#pragma unroll
    for (int o = 0; o < CO_; ++o) {
      float w = wr[o];
      acc[o].x = fmaf(xv.x, w, acc[o].x);
      acc[o].y = fmaf(xv.y, w, acc[o].y);
    }
  }
  float2* ob = (float2*)(off1 + (size_t)b * CO_ * HW_) + r;
#pragma unroll
  for (int o = 0; o < CO_; ++o) ob[o * HW2] = acc[o];
}

// -- Kernel B: 3x3 dil(2) conv (32->32) -> sample coords, 4 px/thread (f32x4) --
__global__ __launch_bounds__(128) void k_coords(const float* __restrict__ off1,
                                                const float* __restrict__ wo2T,
                                                float* __restrict__ coords) {
  constexpr int HW4 = HW_ / 4;   // 2304
  constexpr int W4 = W_ / 4;     // 24
  int p4 = blockIdx.x * 128 + threadIdx.x;  // 36864 threads
  int b = p4 / HW4, r = p4 % HW4;
  int h = r / W4, q = r % W4;    // pixel block: row h, cols 4q..4q+3
  int w0 = q * 4;

  f32x4 acc4[CO_];
#pragma unroll
  for (int o = 0; o < CO_; ++o) acc4[o] = (f32x4){0.f, 0.f, 0.f, 0.f};
  const float* ib = off1 + (size_t)b * CO_ * HW_;
  const f32x4 f4z = (f32x4){0.f, 0.f, 0.f, 0.f};

#pragma unroll
  for (int ky = 0; ky < 3; ++ky) {
    int hh = h + 2 * (ky - 1);
    if ((unsigned)hh < (unsigned)H_) {
      const float* rbase = ib + hh * W_;
      for (int ci = 0; ci < CO_; ++ci) {
        const f32x4* rp = (const f32x4*)(rbase + ci * HW_);
        f32x4 M = rp[q];
        f32x4 Lr = rp[q > 0 ? q - 1 : 0];
        f32x4 Rr = rp[q < W4 - 1 ? q + 1 : W4 - 1];
        f32x4 L = q > 0 ? Lr : f4z;          // zero-pad left border
        f32x4 R = q < W4 - 1 ? Rr : f4z;     // zero-pad right border
        f32x4 v0 = (f32x4){L[2], L[3], M[0], M[1]};   // cols w0-2..w0+1
        f32x4 v2 = (f32x4){M[2], M[3], R[0], R[1]};   // cols w0+2..w0+5
        const float* wr = wo2T + (ci * 9 + ky * 3) * CO_;  // uniform -> s_load
#pragma unroll
        for (int o = 0; o < CO_; ++o) {
          float wk0 = wr[o], wk1 = wr[CO_ + o], wk2 = wr[2 * CO_ + o];
#pragma unroll
          for (int j = 0; j < 4; ++j)
            acc4[o][j] = fmaf(v0[j], wk0,
                         fmaf(M[j], wk1, fmaf(v2[j], wk2, acc4[o][j])));
        }
      }
    }
  }

  float cw[4];
#pragma unroll
  for (int j = 0; j < 4; ++j)
    cw[j] = (float)(w0 + j) + sinf((float)M_PI * (float)(w0 + j + 1) / (float)W_);
  float chv = (float)h + sinf((float)M_PI * (float)(h + 1) / (float)H_);

  float* cb = coords + (size_t)b * G_ * HO_ * WO_ * 2;
#pragma unroll
  for (int g = 0; g < G_; ++g) {
#pragma unroll
    for (int sh = 0; sh < S_; ++sh) {
      f32x4 vo[4];
#pragma unroll
      for (int j = 0; j < 4; ++j) {
#pragma unroll
        for (int sw = 0; sw < S_; ++sw) {
          int idx = g * 4 + sh * 2 + sw;
          float offx = acc4[idx][j] * 0.25f + (sw ? 0.25f : -0.25f);
          float offy = acc4[16 + idx][j] * 0.25f + (sh ? 0.25f : -0.25f);
          float ix = fminf(fmaxf(cw[j] + offx - 0.5f, 0.f), (float)(W_ - 1));
          float iy = fminf(fmaxf(chv + offy - 0.5f, 0.f), (float)(H_ - 1));
          vo[j][sw * 2 + 0] = ix;
          vo[j][sw * 2 + 1] = iy;
        }
      }
      f32x4* dst = (f32x4*)(cb + (((size_t)g * HO_ + 2 * h + sh) * WO_ + 2 * w0) * 2);
#pragma unroll
      for (int j = 0; j < 4; ++j) dst[j] = vo[j];
    }
  }
}

// -- Kernel C: grid_sample (f16 LDS) + dw3x3+BN+ReLU (2 half-passes) + MFMA --
__global__ __launch_bounds__(256, 4) void k_fused(
    const float* __restrict__ x, const float* __restrict__ coords,
    const _Float16* __restrict__ wpwH, const float* __restrict__ Wdw,
    const float* __restrict__ bn_gamma, const float* __restrict__ bn_beta,
    const float* __restrict__ bn_mean, const float* __restrict__ bn_var,
    const float* __restrict__ bpw, float* __restrict__ out) {
  __shared__ __align__(16) unsigned char pool[POOL_BYTES];  // up + ylds16 / clds16
  __shared__ float wdwS[9][C_];   // dw weights pre-scaled by BN scale
  __shared__ float bias2[C_];     // beta - mean*scale
  __shared__ float bp[COUT_];

  _Float16 (*up)[UPS_F] = (_Float16(*)[UPS_F])pool;
  _Float16 (*ylds16)[YROW16] = (_Float16(*)[YROW16])(pool + UP_BYTES);

  for (int i = threadIdx.x; i < C_ * 9; i += 256) {
    int c = i / 9, t = i % 9;
    float sc = bn_gamma[c] * rsqrtf(bn_var[c] + 1e-5f);
    wdwS[t][c] = Wdw[i] * sc;
  }
  for (int i = threadIdx.x; i < C_; i += 256) {
    float sc = bn_gamma[i] * rsqrtf(bn_var[i] + 1e-5f);
    bias2[i] = bn_beta[i] - bn_mean[i] * sc;
  }
  if (threadIdx.x < COUT_) bp[threadIdx.x] = bpw[threadIdx.x];

  constexpr int TILES_W = WO_ / TW_;            // 12
  constexpr int TILES = TILES_W * (HO_ / TH_);  // 144
  int b = blockIdx.x / TILES;
  int t = blockIdx.x % TILES;
  int oh0 = (t / TILES_W) * TH_;
  int ow0 = (t % TILES_W) * TW_;
  int tid = threadIdx.x;
  int py = tid / TW_, px = tid % TW_;
  int lane = tid & 63, wv_ = tid >> 6;
  int lr = lane & 15, lk = lane >> 4;

  f32x4 acc[4][4];
#pragma unroll
  for (int mt = 0; mt < 4; ++mt)
#pragma unroll
    for (int nt = 0; nt < 4; ++nt) acc[mt][nt] = (f32x4){0.f, 0.f, 0.f, 0.f};

  for (int g = 0; g < G_; ++g) {
    __syncthreads();  // covers init loads; protects `up` reuse across g
    const float* xg = x + ((size_t)b * C_ + g * CPG_) * HW_;
    const float* cbase = coords + (((size_t)b * G_ + g) * HO_ * WO_) * 2;
    // ---- sampling: work item = (halo position, channel-octet) ----
    for (int wi = tid; wi < NPOS * 4; wi += 256) {
      int p = wi >> 2, cq = wi & 3;
      int hy = oh0 + p / HALO_W - 1;
      int hx = ow0 + p % HALO_W - 1;
      _Float16* dst = &up[p][cq * 8];
      if (hy < 0 || hy >= HO_ || hx < 0 || hx >= WO_) {
#pragma unroll
        for (int j2 = 0; j2 < 4; ++j2)
          *(f16x2*)&dst[2 * j2] = (f16x2){(_Float16)0.f, (_Float16)0.f};
      } else {
        float2 c2 = *(const float2*)&cbase[((size_t)hy * WO_ + hx) * 2];
        float ix = c2.x, iy = c2.y;
        float x0f = floorf(ix), y0f = floorf(iy);
        float wx = ix - x0f, wy = iy - y0f;
        int x0 = (int)x0f, y0 = (int)y0f;  // already in [0, 95]
        int x1 = min(x0 + 1, W_ - 1);
        int y1 = min(y0 + 1, H_ - 1);
        float w00 = (1.f - wx) * (1.f - wy);
        float w01 = wx * (1.f - wy);
        float w10 = (1.f - wx) * wy;
        float w11 = wx * wy;
        const float* r0 = xg + (size_t)(cq * 8) * HW_ + y0 * W_;
        const float* r1 = xg + (size_t)(cq * 8) * HW_ + y1 * W_;
#pragma unroll
        for (int j2 = 0; j2 < 4; ++j2) {
          int offA = (2 * j2) * HW_, offB = offA + HW_;
          float v0 = w00 * r0[offA + x0] + w01 * r0[offA + x1] +
                     w10 * r1[offA + x0] + w11 * r1[offA + x1];
          float v1 = w00 * r0[offB + x0] + w01 * r0[offB + x1] +
                     w10 * r1[offB + x0] + w11 * r1[offB + x1];
          *(f16x2*)&dst[2 * j2] = (f16x2){(_Float16)v0, (_Float16)v1};
        }
      }
    }
    __syncthreads();

    // ---- dw3x3+BN+ReLU in two 16-channel half-passes; A-frags by lane half ----
    f16x8 afr[4] = {};
#pragma unroll
    for (int half = 0; half < 2; ++half) {
      if (half) __syncthreads();  // ylds16 overwrite after half-0 frag loads
#pragma unroll
      for (int cp = 0; cp < 8; ++cp) {
        int cl = 2 * cp;                       // channel-in-half
        int c = g * CPG_ + half * 16 + cl;     // global channel
        float dw0 = bias2[c], dw1 = bias2[c + 1];
#pragma unroll
        for (int tt = 0; tt < 9; ++tt) {
          int dy = tt / 3, dx = tt % 3;
          f16x2 pk = *(const f16x2*)&up[(py + dy) * HALO_W + px + dx][half * 16 + cl];
          float2 wv = *(const float2*)&wdwS[tt][c];
          dw0 = fmaf((float)pk.x, wv.x, dw0);
          dw1 = fmaf((float)pk.y, wv.y, dw1);
        }
        *(f16x2*)&ylds16[tid][cl] =
            (f16x2){(_Float16)fmaxf(dw0, 0.f), (_Float16)fmaxf(dw1, 0.f)};
      }
      __syncthreads();
      if ((lk >> 1) == half) {  // this lane's k-slot lives in this half
#pragma unroll
        for (int mt = 0; mt < 4; ++mt)
          afr[mt] = *(const f16x8*)&ylds16[(wv_ * 4 + mt) * 16 + lr][(lk & 1) * 8];
      }
    }
    // ---- one K=32 MFMA set per g ----
#pragma unroll
    for (int nt = 0; nt < 4; ++nt) {
      f16x8 bfr = *(const f16x8*)&wpwH[(nt * 16 + lr) * C_ + g * CPG_ + lk * 8];
#pragma unroll
      for (int mt = 0; mt < 4; ++mt)
        acc[mt][nt] = __builtin_amdgcn_mfma_f32_16x16x32_f16(afr[mt], bfr,
                                                             acc[mt][nt], 0, 0, 0);
    }
  }

  // ---- epilogue: 4 rounds of 16 channels via clds16 overlay ----
  float (*clds16)[257] = (float(*)[257])pool;  // [16][257] = 16448 B
  int oh = oh0 + py, ow = ow0 + px;
#pragma unroll
  for (int hq = 0; hq < 4; ++hq) {
    __syncthreads();  // first iter: all waves done with up/ylds16
#pragma unroll
    for (int mt = 0; mt < 4; ++mt) {
#pragma unroll
      for (int r = 0; r < 4; ++r)
        clds16[lr][(wv_ * 4 + mt) * 16 + lk * 4 + r] = acc[mt][hq][r];
    }
    __syncthreads();
#pragma unroll
    for (int i = 0; i < 16; ++i) {
      int o = hq * 16 + i;
      out[(((size_t)b * COUT_ + o) * HO_ + oh) * WO_ + ow] = clds16[i][tid] + bp[o];
    }
  }
}

extern "C" void kernel_launch(void* const* d_in, const int* in_sizes, int n_in,
                              void* d_out, int out_size, void* d_ws, size_t ws_size,
                              hipStream_t stream) {
  const float* x        = (const float*)d_in[0];
  const float* Wo1      = (const float*)d_in[1];
  const float* bo1      = (const float*)d_in[2];
  const float* Wo2      = (const float*)d_in[3];
  const float* Wdw      = (const float*)d_in[4];
  const float* bn_gamma = (const float*)d_in[5];
  const float* bn_beta  = (const float*)d_in[6];
  const float* bn_mean  = (const float*)d_in[7];
  const float* bn_var   = (const float*)d_in[8];
  const float* Wpw      = (const float*)d_in[9];
  const float* bpw      = (const float*)d_in[10];
  float* out = (float*)d_out;

  float* ws = (float*)d_ws;
  float* off1        = ws + WS_OFF1;
  float* coords      = ws + WS_COORDS;
  _Float16* wpwH     = (_Float16*)(ws + WS_WPWH);
  float* wo1T        = ws + WS_WO1T;
  float* wo2T        = ws + WS_WO2T;

  k_prep  <<<(C_ * COUT_ + C_ * CO_ + CO_ * CO_ * 9 + 255) / 256, 256, 0, stream>>>(
      Wpw, Wo1, Wo2, wpwH, wo1T, wo2T);
  k_off1  <<<(B_ * HW_ / 2) / 256, 256, 0, stream>>>(x, wo1T, bo1, off1);
  k_coords<<<(B_ * HW_ / 4) / 128, 128, 0, stream>>>(off1, wo2T, coords);
  k_fused <<<B_ * 144, 256, 0, stream>>>(x, coords, wpwH, Wdw, bn_gamma,
                                         bn_beta, bn_mean, bn_var, bpw, out);
}